// Round 13
// baseline (39.571 us; speedup 1.0000x reference)
//
#include <hip/hip_runtime.h>
#include <stdint.h>
#include <stddef.h>

typedef _Float16 f16;
typedef _Float16 f16x2 __attribute__((ext_vector_type(2)));
typedef _Float16 f16x4 __attribute__((ext_vector_type(4)));
typedef _Float16 f16x8 __attribute__((ext_vector_type(8)));
typedef float f32x16 __attribute__((ext_vector_type(16)));

#define INNER_SZ 4225
#define NQ 164          // ksteps: 160 quad (sym-folded, row-rounded) + 4 linear
#define XSTR 72
#define NPH 41          // phases of 4 ksteps

// ---------------- prep: symmetric fold + granule-packed f16 (verified R9-R12) ----
// Wf2 layout: [q][2048B] = [q][ng(2)][64 granules(16B)][8 f16], granule G = 2c+h.
__global__ __launch_bounds__(256) void cm_prep(const float* __restrict__ W,
                                               const float* __restrict__ bias,
                                               f16* __restrict__ Wf2,
                                               float* __restrict__ cvec) {
  int idx = blockIdx.x * 256 + threadIdx.x;
  if (idx < NQ * 1024) {
    int q   = idx >> 10;
    int r10 = idx & 1023;
    int ngh = r10 >> 9;
    int rr  = r10 & 511;
    int G   = rr >> 3;
    int e   = rr & 7;
    int c = G >> 1, hh = G & 1;
    int o = ngh * 32 + c;
    int kl = hh * 8 + e;
    float v = 0.f;
    if (q < 160) {
      int b, start;
      if (q < 16)      { b = 0; start = 0;  }
      else if (q < 48) { b = 1; start = 16; }
      else if (q < 96) { b = 2; start = 48; }
      else             { b = 3; start = 96; }
      int rel = q - start;
      int i = 16 * b + rel / (b + 1);
      int s = rel % (b + 1);
      int j = s * 16 + kl;
      if (j < i)
        v = W[o * INNER_SZ + (i + 1) * 65 + (j + 1)] +
            W[o * INNER_SZ + (j + 1) * 65 + (i + 1)];
      else if (j == i)
        v = W[o * INNER_SZ + (i + 1) * 65 + (i + 1)];
    } else {
      int j = (q - 160) * 16 + kl;
      v = W[o * INNER_SZ + (j + 1)] + W[o * INNER_SZ + (j + 1) * 65];
    }
    Wf2[idx] = (f16)v;
  }
  if (idx < 64) cvec[idx] = W[idx * INNER_SZ] + bias[idx];
}

// global -> LDS direct, 16B/lane (wave-uniform dest base + lane*16)
__device__ inline void gload_lds16(const void* gp, void* lp) {
  __builtin_amdgcn_global_load_lds(
      (const __attribute__((address_space(1))) uint32_t*)(uintptr_t)gp,
      (__attribute__((address_space(3))) uint32_t*)(uintptr_t)lp, 16, 0, 0);
}

__device__ __forceinline__ f16x8 mulsp(f16x2 sp, f16x8 wv) {
  f16x8 r;
#pragma unroll
  for (int e = 0; e < 4; ++e)
    ((f16x2*)&r)[e] = sp * ((const f16x2*)&wv)[e];
  return r;
}

// ---------------- main fused kernel ----------------
// grid 512 x 256 threads (4 waves). Block tile: 128 rows x 64 cols.
// Wave (rowg=w&1, ch=w>>1): rows rowg*64+[0,64) (acc0/acc1), cols ch*32+[0,32),
// full K = 164 ksteps. W staged via DMA in 4-kstep phases (8 KB), ring-2,
// one __syncthreads per phase (vmcnt(0) drain amortized over ~1000cyc compute).
// Per kstep per wave: 1 ds_read_b128 (shared by 2 MFMAs) + 4 pk_mul. 4 blk/CU.
__global__ __launch_bounds__(256, 4) void cm_main(
    const float* __restrict__ x, const f16* __restrict__ Wf2,
    const float* __restrict__ cvec, const float* __restrict__ gamma,
    const float* __restrict__ beta, float* __restrict__ out) {
  __shared__ __align__(16) union SM {
    struct { f16 ring[2][4096]; f16 xs[128 * XSTR]; } k;  // 16 KB + 18 KB
    float yt[8192];                                       // 32 KB epilogue (aliases)
  } sm;

  const int tid = threadIdx.x;
  const int lane = tid & 63;
  const int w = tid >> 6;
  const int rowg = w & 1;
  const int ch = w >> 1;
  const int c31 = lane & 31;
  const int h = lane >> 5;
  const long mbase = (long)blockIdx.x * 128;

  const char* wsrc = (const char*)Wf2 + lane * 16;
  char* ringb = (char*)&sm.k.ring[0][0];

  // wave w stages kstep (4p + w): 2 KB as two 1KB DMAs
#define STAGE2(P)                                                           \
  do {                                                                      \
    const char* s_ = wsrc + (size_t)(4 * (P) + w) * 2048;                   \
    char* d_ = ringb + (((P) & 1) ? 8192 : 0) + w * 2048;                   \
    gload_lds16(s_, d_);                                                    \
    gload_lds16(s_ + 1024, d_ + 1024);                                      \
  } while (0)

  STAGE2(0);

  // ---- x tile -> LDS f16 [128][72] ----
#pragma unroll
  for (int it = 0; it < 8; ++it) {
    int idx = it * 1024 + tid * 4;
    int row = idx >> 6, col = idx & 63;
    const float4 v = *(const float4*)(x + (size_t)(mbase + row) * 64 + col);
    f16x4 hv = {(f16)v.x, (f16)v.y, (f16)v.z, (f16)v.w};
    *(f16x4*)(sm.k.xs + row * XSTR + col) = hv;
  }
  __syncthreads();   // xs visible + stage(0) landed

  const int r0 = rowg * 64 + c31, r1 = rowg * 64 + 32 + c31;
  f16x8 xw0[4], xw1[4];
#pragma unroll
  for (int s = 0; s < 4; ++s) {
    xw0[s] = *(const f16x8*)(sm.k.xs + r0 * XSTR + s * 16 + h * 8);
    xw1[s] = *(const f16x8*)(sm.k.xs + r1 * XSTR + s * 16 + h * 8);
  }
#pragma unroll
  for (int s = 0; s < 4; ++s)   // pin windows in registers
    asm volatile("" : "+v"(xw0[s]), "+v"(xw1[s]));

  const int bfo = ch * 1024 + (2 * c31 + h) * 16;   // B-frag offset within kstep slab

  f32x16 acc0 = (f32x16)(0.0f);
  f32x16 acc1 = (f32x16)(0.0f);
  // x_i prefetch (i = 0)
  uint32_t un0 = *(const uint16_t*)(sm.k.xs + r0 * XSTR);
  uint32_t un1 = *(const uint16_t*)(sm.k.xs + r1 * XSTR);
  f16x2 sp0 = {}, sp1 = {};

  // ---- K loop: 41 phases x 4 ksteps ----
#pragma unroll
  for (int p = 0; p < NPH; ++p) {
    if (p + 1 < NPH) STAGE2(p + 1);
    const char* rb = ringb + ((p & 1) ? 8192 : 0);
#pragma unroll
    for (int kk = 0; kk < 4; ++kk) {
      const int q = 4 * p + kk;
      int i, s, lin;
      if (q >= 160) { i = 64; s = q - 160; lin = 1; }
      else {
        int b = (q < 16) ? 0 : (q < 48) ? 1 : (q < 96) ? 2 : 3;
        int st = (b == 0) ? 0 : (b == 1) ? 16 : (b == 2) ? 48 : 96;
        int rel = q - st;
        i = 16 * b + rel / (b + 1);
        s = rel % (b + 1);
        lin = 0;
      }
      bool newi;
      if (q == 0) newi = true;
      else if (lin) newi = false;
      else {
        int qp = q - 1;
        int bp = (qp < 16) ? 0 : (qp < 48) ? 1 : (qp < 96) ? 2 : 3;
        int stp = (bp == 0) ? 0 : (bp == 1) ? 16 : (bp == 2) ? 48 : 96;
        newi = (16 * bp + (qp - stp) / (bp + 1)) != i;
      }
      if (newi) {
        uint32_t u0 = un0 & 0xffffu, u1 = un1 & 0xffffu;
        sp0 = __builtin_bit_cast(f16x2, u0 | (u0 << 16));
        sp1 = __builtin_bit_cast(f16x2, u1 | (u1 << 16));
        if (i + 1 < 64) {   // prefetch next i (>=1 kstep ahead)
          un0 = *(const uint16_t*)(sm.k.xs + r0 * XSTR + i + 1);
          un1 = *(const uint16_t*)(sm.k.xs + r1 * XSTR + i + 1);
        }
      }
      f16x8 bf = *(const f16x8*)(rb + kk * 2048 + bfo);
      f16x8 a0, a1;
      if (lin) { a0 = xw0[s]; a1 = xw1[s]; }
      else     { a0 = mulsp(sp0, xw0[s]); a1 = mulsp(sp1, xw1[s]); }
      acc0 = __builtin_amdgcn_mfma_f32_32x32x16_f16(a0, bf, acc0, 0, 0, 0);
      acc1 = __builtin_amdgcn_mfma_f32_32x32x16_f16(a1, bf, acc1, 0, 0, 0);
    }
    __syncthreads();   // drains this phase's 2 DMAs (long overlap) + slot handoff
  }

  // ---- epilogue: transpose via swizzled LDS (aliases ring+xs), LN, store ----
  {
    const int cg = ch * 32 + c31;
    const int swz = (c31 & 7) << 4;
#pragma unroll
    for (int rq = 0; rq < 4; ++rq) {
      int b0 = cg * 512 + rowg * 256 + 0 * 128 + rq * 32 + h * 16;
      int b1 = cg * 512 + rowg * 256 + 1 * 128 + rq * 32 + h * 16;
      *(float4*)((char*)sm.yt + (b0 ^ swz)) =
          make_float4(acc0[rq * 4 + 0], acc0[rq * 4 + 1], acc0[rq * 4 + 2], acc0[rq * 4 + 3]);
      *(float4*)((char*)sm.yt + (b1 ^ swz)) =
          make_float4(acc1[rq * 4 + 0], acc1[rq * 4 + 1], acc1[rq * 4 + 2], acc1[rq * 4 + 3]);
    }
  }
  __syncthreads();

  // ---- LayerNorm: 256 threads, one (row, col-half) each ----
  {
    int row = tid >> 1, half = tid & 1;
    float y[32];
    float s = 0.f, qs = 0.f;
#pragma unroll
    for (int j = 0; j < 32; ++j) {
      int c = half * 32 + j;
      int byte = (c * 512 + row * 4) ^ ((c & 7) << 4);
      float v = *(const float*)((const char*)sm.yt + byte);
      v += cvec[c];
      y[j] = v;
      s += v; qs += v * v;
    }
    s  += __shfl_xor(s, 1);
    qs += __shfl_xor(qs, 1);
    float mean = s * 0.015625f;
    float var = qs * 0.015625f - mean * mean;
    float rstd = rsqrtf(var + 1e-6f);
#pragma unroll
    for (int j = 0; j < 32; ++j) {
      int c = half * 32 + j;
      y[j] = gamma[c] * (y[j] - mean) * rstd + beta[c];
    }
    float* op = out + (size_t)(mbase + row) * 64 + half * 32;
#pragma unroll
    for (int j4 = 0; j4 < 8; ++j4)
      *(float4*)(op + j4 * 4) =
          make_float4(y[j4 * 4 + 0], y[j4 * 4 + 1], y[j4 * 4 + 2], y[j4 * 4 + 3]);
  }
#undef STAGE2
}

extern "C" void kernel_launch(void* const* d_in, const int* in_sizes, int n_in,
                              void* d_out, int out_size, void* d_ws, size_t ws_size,
                              hipStream_t stream) {
  const float* x     = (const float*)d_in[0];
  const float* W     = (const float*)d_in[1];
  const float* bias  = (const float*)d_in[2];
  const float* gamma = (const float*)d_in[3];
  const float* beta  = (const float*)d_in[4];
  float* out = (float*)d_out;

  f16* Wf2 = (f16*)d_ws;                                   // 164*1024*2 = 335872 B
  float* cvec = (float*)((char*)d_ws + NQ * 1024 * 2);     // 64 f32

  cm_prep<<<(NQ * 1024 + 255) / 256, 256, 0, stream>>>(W, bias, Wf2, cvec);
  cm_main<<<512, 256, 0, stream>>>(x, Wf2, cvec, gamma, beta, out);
}